// Round 13
// baseline (86.216 us; speedup 1.0000x reference)
//
#include <hip/hip_runtime.h>
#include <math.h>

#define DEVFN __device__ __forceinline__

typedef __attribute__((ext_vector_type(8))) _Float16 f16x8;
typedef __attribute__((ext_vector_type(4))) float f32x4;

DEVFN float shxor(float v, int m) { return __shfl_xor(v, m, 64); }

// ---------------------------------------------------------------------------
// Gate machinery (verified R1/R3/R4/R5).
// State layout: amplitude index a (8 bits) = lane*4 + k; wire w <-> bit 7-w.
// ---------------------------------------------------------------------------
template<int W>
DEVFN void rot_gate(int lane, float (&sr)[4], float (&si)[4], const float* u) {
  const float u00r=u[0], u00i=u[1], u01r=u[2], u01i=u[3];
  const float u10r=u[4], u10i=u[5], u11r=u[6], u11i=u[7];
  if constexpr (W <= 5) {
    constexpr int M = 1 << (5 - W);
    const bool hi = (lane & M) != 0;
    const float cmr = hi ? u11r : u00r, cmi = hi ? u11i : u00i;
    const float cor = hi ? u10r : u01r, coi = hi ? u10i : u01i;
    #pragma unroll
    for (int k = 0; k < 4; ++k) {
      float orr = shxor(sr[k], M);
      float oii = shxor(si[k], M);
      float nr = cmr*sr[k] - cmi*si[k] + cor*orr - coi*oii;
      float ni = cmr*si[k] + cmi*sr[k] + cor*oii + coi*orr;
      sr[k] = nr; si[k] = ni;
    }
  } else {
    constexpr int KB = (W == 6) ? 2 : 1;
    #pragma unroll
    for (int k0 = 0; k0 < 4; ++k0) {
      if ((k0 & KB) == 0) {
        const int k1 = k0 | KB;
        float ar = sr[k0], ai = si[k0];
        float br = sr[k1], bi = si[k1];
        sr[k0] = u00r*ar - u00i*ai + u01r*br - u01i*bi;
        si[k0] = u00r*ai + u00i*ar + u01r*bi + u01i*br;
        sr[k1] = u10r*ar - u10i*ai + u11r*br - u11i*bi;
        si[k1] = u10r*ai + u10i*ar + u11r*bi + u11i*br;
      }
    }
  }
}

template<int C, int T>
DEVFN void cnot_gate(int lane, float (&sr)[4], float (&si)[4]) {
  constexpr int PC = 7 - C, PT = 7 - T;
  if constexpr (PT >= 2) {
    constexpr int M = 1 << (PT - 2);
    #pragma unroll
    for (int k = 0; k < 4; ++k) {
      float orr = shxor(sr[k], M);
      float oii = shxor(si[k], M);
      bool ctrl;
      if constexpr (PC >= 2) ctrl = ((lane >> (PC - 2)) & 1) != 0;
      else                   ctrl = ((k >> PC) & 1) != 0;
      if (ctrl) { sr[k] = orr; si[k] = oii; }
    }
  } else {
    float tr[4], ti[4];
    #pragma unroll
    for (int k = 0; k < 4; ++k) { tr[k] = sr[k]; ti[k] = si[k]; }
    #pragma unroll
    for (int k = 0; k < 4; ++k) {
      bool ctrl;
      if constexpr (PC >= 2) ctrl = ((lane >> (PC - 2)) & 1) != 0;
      else                   ctrl = ((k >> PC) & 1) != 0;
      if (ctrl) { sr[k] = tr[k ^ (1 << PT)]; si[k] = ti[k ^ (1 << PT)]; }
    }
  }
}

// ---------------------------------------------------------------------------
// Prep (identical to validated R5/R7): blocks 0..255 simulate basis state
// e_col and scatter into per-wave MFMA fragment layout:
//   Bfrag[((ch*4 + q)*8 + ks)*512 + (kg*16 + cf)*8 + e]
// Block 256: folded LayerNorm/FC stats.
// ---------------------------------------------------------------------------
__global__ __launch_bounds__(64) void qsb_prep(
    const float* __restrict__ qw, const float* __restrict__ Wm,
    const float* __restrict__ bias,
    _Float16* __restrict__ Bfrag, float* __restrict__ stats) {
  __shared__ float uL[16 * 8];
  int bid = blockIdx.x;
  int lane = threadIdx.x;
  if (bid < 256) {
    if (lane < 16) {
      int l = lane >> 3, i = lane & 7;
      float phi = qw[l*24 + i*3 + 0];
      float th  = qw[l*24 + i*3 + 1];
      float om  = qw[l*24 + i*3 + 2];
      float cth = cosf(0.5f*th), sth = sinf(0.5f*th);
      float ap = 0.5f*(phi+om), am = 0.5f*(phi-om);
      float cap = cosf(ap), sap = sinf(ap);
      float cam = cosf(am), sam = sinf(am);
      float* u = &uL[lane*8];
      u[0] =  cap*cth; u[1] = -sap*cth;
      u[2] = -cam*sth; u[3] = -sam*sth;
      u[4] =  cam*sth; u[5] = -sam*sth;
      u[6] =  cap*cth; u[7] =  sap*cth;
    }
    __syncthreads();
    int col = bid;
    float sr[4], si[4];
    #pragma unroll
    for (int k = 0; k < 4; ++k) { sr[k] = (lane*4 + k == col) ? 1.f : 0.f; si[k] = 0.f; }
    rot_gate<0>(lane, sr, si, &uL[0*8]);
    rot_gate<1>(lane, sr, si, &uL[1*8]);
    rot_gate<2>(lane, sr, si, &uL[2*8]);
    rot_gate<3>(lane, sr, si, &uL[3*8]);
    rot_gate<4>(lane, sr, si, &uL[4*8]);
    rot_gate<5>(lane, sr, si, &uL[5*8]);
    rot_gate<6>(lane, sr, si, &uL[6*8]);
    rot_gate<7>(lane, sr, si, &uL[7*8]);
    cnot_gate<0,1>(lane, sr, si);
    cnot_gate<1,2>(lane, sr, si);
    cnot_gate<2,3>(lane, sr, si);
    cnot_gate<3,4>(lane, sr, si);
    cnot_gate<4,5>(lane, sr, si);
    cnot_gate<5,6>(lane, sr, si);
    cnot_gate<6,7>(lane, sr, si);
    cnot_gate<7,0>(lane, sr, si);
    rot_gate<0>(lane, sr, si, &uL[(8+0)*8]);
    rot_gate<1>(lane, sr, si, &uL[(8+1)*8]);
    rot_gate<2>(lane, sr, si, &uL[(8+2)*8]);
    rot_gate<3>(lane, sr, si, &uL[(8+3)*8]);
    rot_gate<4>(lane, sr, si, &uL[(8+4)*8]);
    rot_gate<5>(lane, sr, si, &uL[(8+5)*8]);
    rot_gate<6>(lane, sr, si, &uL[(8+6)*8]);
    rot_gate<7>(lane, sr, si, &uL[(8+7)*8]);
    cnot_gate<0,2>(lane, sr, si);
    cnot_gate<1,3>(lane, sr, si);
    cnot_gate<2,4>(lane, sr, si);
    cnot_gate<3,5>(lane, sr, si);
    cnot_gate<4,6>(lane, sr, si);
    cnot_gate<5,7>(lane, sr, si);
    cnot_gate<6,0>(lane, sr, si);
    cnot_gate<7,1>(lane, sr, si);
    const int ks = col >> 5, kg = (col >> 3) & 3, e = col & 7;
    #pragma unroll
    for (int k = 0; k < 4; ++k) {
      int a = lane*4 + k;
      int ch = a >> 5, nf = (a >> 4) & 1, cf = a & 15;
      int pos = (kg*16 + cf)*8 + e;
      Bfrag[((ch*4 + nf    )*8 + ks)*512 + pos] = (_Float16)sr[k];
      Bfrag[((ch*4 + 2 + nf)*8 + ks)*512 + pos] = (_Float16)si[k];
    }
  } else {
    int t = lane;
    {
      int i = t >> 3, j = t & 7;
      float s = 0.f;
      for (int c = 0; c < 64; ++c) s += Wm[i*64 + c] * Wm[j*64 + c];
      stats[16 + t] = s * 0.015625f;
    }
    if (t < 8) {
      float s = 0.f, sb = 0.f;
      for (int c = 0; c < 64; ++c) { float w = Wm[t*64 + c]; s += w; sb += w * bias[c]; }
      stats[t]     = s * 0.015625f;
      stats[8 + t] = 2.f * sb * 0.015625f;
    }
    if (t == 0) {
      float s = 0.f, s2 = 0.f;
      for (int c = 0; c < 64; ++c) { s += bias[c]; s2 += bias[c]*bias[c]; }
      stats[80] = s * 0.015625f;
      stats[81] = s2 * 0.015625f;
    }
  }
}

// ---------------------------------------------------------------------------
// Main (R7 numerics, PERSISTENT, spill-safe): grid = 512 blocks, each loops
// over 2 row-tiles of 32 rows. Per tile EXACT R7 body: phase1 A-build ->
// per-chunk {just-in-time bqA/bqB double-buffered GEMM -> probs -> Y
// transpose -> S-MFMA -> zpart} -> combine+LN -> FC+GELU.
// No rotating register banks (R11's s%3 indexing spilled to scratch —
// rule #20); only loop-carried state is `tile`.
// Amp bits: b7b6b5 = chunk, b4 = nf, b3..b0 = cf; wire w <-> bit 7-w.
// ---------------------------------------------------------------------------
__global__ __launch_bounds__(256, 4) void qsb_main(
    const float* __restrict__ pca, const _Float16* __restrict__ Bfrag,
    const float* __restrict__ statsG,
    const float* __restrict__ Wm, const float* __restrict__ bias,
    const float* __restrict__ gamma, const float* __restrict__ beta,
    float* __restrict__ out, int B) {
  // A3: element (row,k): ((ks*2 + m)*16 + cf)*32 + (kg^(ks&3))*8 + e  (16 KB)
  __shared__ __align__(16) _Float16 A3[8192];
  __shared__ __align__(16) _Float16 YL[4 * 1280];  // per-wave Y, stride 40 (10 KB)
  __shared__ float zpart[2304];   // [ch=8][row=32][9], slots 0..5 used (9 KB)
  __shared__ float zrow[256];     // [row=32][8]
  __shared__ float musig[64];     // [row=32][2]
  __shared__ float Wl[512];
  __shared__ float biasL[64], gammaL[64], betaL[64];
  __shared__ float statsL[82];

  const int tid = threadIdx.x;
  const int wid = tid >> 6, lane = tid & 63;
  const int cfrag = lane & 15, kgrp = lane >> 4;

  // ---- phase 0: preloads (once) ----
  #pragma unroll
  for (int i = tid; i < 512; i += 256) Wl[i] = Wm[i];
  if (tid >= 256 - 64) {
    int t = tid - (256 - 64);
    biasL[t] = bias[t]; gammaL[t] = gamma[t]; betaL[t] = beta[t];
  }
  if (tid < 82) statsL[tid] = statsG[tid];

  // ---- sign fragment for the S-MFMA (once) ----
  f16x8 sfrag;
  #pragma unroll
  for (int e = 0; e < 8; ++e) {
    float v;
    if      (cfrag == 0) v = 1.f;                        // T (chunk total)
    else if (cfrag == 1) v = (kgrp & 2) ? -1.f : 1.f;    // wire 3 (a bit4)
    else if (cfrag == 2) v = (kgrp & 1) ? -1.f : 1.f;    // wire 4 (a bit3)
    else if (cfrag == 3) v = (e & 4)    ? -1.f : 1.f;    // wire 5 (a bit2)
    else if (cfrag == 4) v = (e & 2)    ? -1.f : 1.f;    // wire 6 (a bit1)
    else if (cfrag == 5) v = (e & 1)    ? -1.f : 1.f;    // wire 7 (a bit0)
    else v = 0.f;
    sfrag[e] = (_Float16)v;
  }

  _Float16* Yw = &YL[wid * 1280];
  const int ntile = (B + 31) >> 5;

  for (int tile = blockIdx.x; tile < ntile; tile += gridDim.x) {
    const int r0 = tile * 32;
    __syncthreads();   // tile barrier: protect A3/zpart/zrow/musig reuse

    // ---- phase 1: A build (8 threads/row, 32 k each), fast trig ----
    {
      const int rl = tid >> 3, tq = tid & 7;
      const int r = r0 + rl;
      float cv[8], sv[8];
      #pragma unroll
      for (int w = 0; w < 8; ++w) { cv[w] = 1.f; sv[w] = 0.f; }
      if (r < B) {
        #pragma unroll
        for (int w = 0; w < 8; ++w) {
          float x = pca[r*8 + w];
          float sg = __builtin_amdgcn_rcpf(1.f + __expf(-x));
          float ang = 1.5707963267948966f * sg;
          cv[w] = __cosf(ang); sv[w] = __sinf(ang);
        }
      }
      float base = ((tq & 4) ? sv[0] : cv[0]) * ((tq & 2) ? sv[1] : cv[1])
                 * ((tq & 1) ? sv[2] : cv[2]);
      float arr[32];
      arr[0] = base;
      #pragma unroll
      for (int p = 0; p < 5; ++p) {
        const int w = 7 - p;
        const int sz = 1 << p;
        #pragma unroll
        for (int i = 0; i < (1 << p); ++i) {
          arr[i + sz] = arr[i] * sv[w];
          arr[i]      = arr[i] * cv[w];
        }
      }
      _Float16* dstBase = &A3[((tq*2 + (rl >> 4))*16 + (rl & 15))*32];
      #pragma unroll
      for (int ib = 0; ib < 4; ++ib) {
        f16x8 v;
        #pragma unroll
        for (int j = 0; j < 8; ++j) v[j] = (_Float16)arr[ib*8 + j];
        *(f16x8*)(dstBase + (ib ^ (tq & 3))*8) = v;
      }
    }
    __syncthreads();   // barrier 1: A3 ready

    // ---- phases 2+3, per chunk (exact R7 body) ----
    #pragma unroll
    for (int c = 0; c < 2; ++c) {
      const int ch = wid*2 + c;
      const _Float16* Bw = Bfrag + (size_t)(ch*4)*8*512 + lane*8;

      f32x4 acc[2][4];
      #pragma unroll
      for (int m = 0; m < 2; ++m)
        #pragma unroll
        for (int q = 0; q < 4; ++q) acc[m][q] = (f32x4){0.f, 0.f, 0.f, 0.f};

      f16x8 bqA[4], bqB[4];
      #pragma unroll
      for (int q = 0; q < 4; ++q) bqA[q] = *(const f16x8*)(Bw + (q*8 + 0)*512);

      #pragma unroll
      for (int kp = 0; kp < 4; ++kp) {
        const int ks0 = kp*2, ks1 = kp*2 + 1;
        #pragma unroll
        for (int q = 0; q < 4; ++q) bqB[q] = *(const f16x8*)(Bw + (q*8 + ks1)*512);
        {
          f16x8 af0 = *(const f16x8*)&A3[((ks0*2 + 0)*16 + cfrag)*32 + (kgrp ^ (ks0 & 3))*8];
          f16x8 af1 = *(const f16x8*)&A3[((ks0*2 + 1)*16 + cfrag)*32 + (kgrp ^ (ks0 & 3))*8];
          #pragma unroll
          for (int q = 0; q < 4; ++q) {
            acc[0][q] = __builtin_amdgcn_mfma_f32_16x16x32_f16(af0, bqA[q], acc[0][q], 0, 0, 0);
            acc[1][q] = __builtin_amdgcn_mfma_f32_16x16x32_f16(af1, bqA[q], acc[1][q], 0, 0, 0);
          }
        }
        if (kp < 3) {
          #pragma unroll
          for (int q = 0; q < 4; ++q) bqA[q] = *(const f16x8*)(Bw + (q*8 + ks0 + 2)*512);
        }
        {
          f16x8 af0 = *(const f16x8*)&A3[((ks1*2 + 0)*16 + cfrag)*32 + (kgrp ^ (ks1 & 3))*8];
          f16x8 af1 = *(const f16x8*)&A3[((ks1*2 + 1)*16 + cfrag)*32 + (kgrp ^ (ks1 & 3))*8];
          #pragma unroll
          for (int q = 0; q < 4; ++q) {
            acc[0][q] = __builtin_amdgcn_mfma_f32_16x16x32_f16(af0, bqB[q], acc[0][q], 0, 0, 0);
            acc[1][q] = __builtin_amdgcn_mfma_f32_16x16x32_f16(af1, bqB[q], acc[1][q], 0, 0, 0);
          }
        }
      }

      // probs -> wave-private Y (f16, A-frag-transposed via LDS, stride 40)
      #pragma unroll
      for (int m = 0; m < 2; ++m) {
        #pragma unroll
        for (int nf = 0; nf < 2; ++nf) {
          #pragma unroll
          for (int j = 0; j < 4; ++j) {
            float re = acc[m][nf][j], im = acc[m][2 + nf][j];
            float p = re*re + im*im;
            Yw[m*640 + (kgrp*4 + j)*40 + nf*16 + cfrag] = (_Float16)p;
          }
        }
      }
      // wave-private read-back (in-order DS pipe; no barrier needed)
      #pragma unroll
      for (int m = 0; m < 2; ++m) {
        f16x8 yfrag = *(const f16x8*)&Yw[m*640 + (lane & 15)*40 + kgrp*8];
        f32x4 d = __builtin_amdgcn_mfma_f32_16x16x32_f16(yfrag, sfrag, (f32x4){0.f,0.f,0.f,0.f}, 0, 0, 0);
        if (cfrag < 6) {
          #pragma unroll
          for (int j = 0; j < 4; ++j)
            zpart[(ch*32 + m*16 + kgrp*4 + j)*9 + cfrag] = d[j];
        }
      }
    }
    __syncthreads();   // barrier 2: zpart ready

    // ---- phase 4+5: combine chunks + LN stats (thread=(row,wire)) ----
    {
      const int row = tid >> 3, w = tid & 7;
      const int slot = (w < 3) ? 0 : (w - 2);
      const int sm = (w == 0) ? 4 : (w == 1) ? 2 : (w == 2) ? 1 : 0;
      float z = 0.f;
      #pragma unroll
      for (int ch = 0; ch < 8; ++ch) {
        float v = zpart[(ch*32 + row)*9 + slot];
        z += (ch & sm) ? -v : v;
      }
      zrow[row*8 + w] = z;
      // same wave wrote all 8 slots of this row -> in-order DS, read back
      f32x4 zlo = *(const f32x4*)&zrow[row*8];
      f32x4 zhi = *(const f32x4*)&zrow[row*8 + 4];
      float zj[8] = {zlo[0], zlo[1], zlo[2], zlo[3], zhi[0], zhi[1], zhi[2], zhi[3]};
      float qi = statsL[8 + w];
      #pragma unroll
      for (int j = 0; j < 8; ++j) qi += statsL[16 + w*8 + j] * zj[j];
      float e2p = zj[w] * qi;
      float mup = statsL[w] * zj[w];
      e2p += shxor(e2p, 1); e2p += shxor(e2p, 2); e2p += shxor(e2p, 4);
      mup += shxor(mup, 1); mup += shxor(mup, 2); mup += shxor(mup, 4);
      if (w == 0) {
        float mu = mup + statsL[80];
        float e2 = e2p + statsL[81];
        float var = e2 - mu*mu;
        musig[row*2]     = mu;
        musig[row*2 + 1] = rsqrtf(fmaxf(var, 0.f) + 1e-5f);
      }
    }
    // no barrier: phase 6 reads only this wave's zrow/musig rows

    // ---- phase 6: FC + LN + exact GELU (8 rows per wave) ----
    #pragma unroll
    for (int rr = 0; rr < 8; ++rr) {
      const int row = wid*8 + rr;
      const int gr = r0 + row;
      float h = biasL[lane];
      #pragma unroll
      for (int i = 0; i < 8; ++i) h = fmaf(zrow[row*8 + i], Wl[i*64 + lane], h);
      float hn = (h - musig[row*2]) * musig[row*2 + 1] * gammaL[lane] + betaL[lane];
      float ge = 0.5f * hn * (1.f + erff(hn * 0.70710678118654752f));
      if (gr < B) out[gr*64 + lane] = ge;
    }
  }
}

extern "C" void kernel_launch(void* const* d_in, const int* in_sizes, int n_in,
                              void* d_out, int out_size, void* d_ws, size_t ws_size,
                              hipStream_t stream) {
  const float* pca   = (const float*)d_in[0];
  const float* qw    = (const float*)d_in[1];
  const float* Wm    = (const float*)d_in[2];
  const float* bias  = (const float*)d_in[3];
  const float* gamma = (const float*)d_in[4];
  const float* beta  = (const float*)d_in[5];
  float* out = (float*)d_out;

  _Float16* Bfrag = (_Float16*)d_ws;                   // 512*256*2 = 256 KiB
  float* stats = (float*)((char*)d_ws + 512*256*2);    // 82 floats

  int B = in_sizes[0] / 8;

  hipLaunchKernelGGL(qsb_prep, dim3(257), dim3(64), 0, stream, qw, Wm, bias, Bfrag, stats);
  int ntile = (B + 31) / 32;
  int blocks = ntile < 512 ? ntile : 512;   // persistent: 2 tiles/block at B=32768
  hipLaunchKernelGGL(qsb_main, dim3(blocks), dim3(256), 0, stream,
                     pca, Bfrag, stats, Wm, bias, gamma, beta, out, B);
}

// Round 14
// 50.596 us; speedup vs baseline: 1.7040x; 1.7040x over previous
//
#include <hip/hip_runtime.h>
#include <math.h>

#define DEVFN __device__ __forceinline__

typedef __attribute__((ext_vector_type(8))) _Float16 f16x8;
typedef __attribute__((ext_vector_type(4))) float f32x4;

DEVFN float shxor(float v, int m) { return __shfl_xor(v, m, 64); }

// ---------------------------------------------------------------------------
// Gate machinery (verified R1/R3/R4/R5).
// State layout: amplitude index a (8 bits) = lane*4 + k; wire w <-> bit 7-w.
// ---------------------------------------------------------------------------
template<int W>
DEVFN void rot_gate(int lane, float (&sr)[4], float (&si)[4], const float* u) {
  const float u00r=u[0], u00i=u[1], u01r=u[2], u01i=u[3];
  const float u10r=u[4], u10i=u[5], u11r=u[6], u11i=u[7];
  if constexpr (W <= 5) {
    constexpr int M = 1 << (5 - W);
    const bool hi = (lane & M) != 0;
    const float cmr = hi ? u11r : u00r, cmi = hi ? u11i : u00i;
    const float cor = hi ? u10r : u01r, coi = hi ? u10i : u01i;
    #pragma unroll
    for (int k = 0; k < 4; ++k) {
      float orr = shxor(sr[k], M);
      float oii = shxor(si[k], M);
      float nr = cmr*sr[k] - cmi*si[k] + cor*orr - coi*oii;
      float ni = cmr*si[k] + cmi*sr[k] + cor*oii + coi*orr;
      sr[k] = nr; si[k] = ni;
    }
  } else {
    constexpr int KB = (W == 6) ? 2 : 1;
    #pragma unroll
    for (int k0 = 0; k0 < 4; ++k0) {
      if ((k0 & KB) == 0) {
        const int k1 = k0 | KB;
        float ar = sr[k0], ai = si[k0];
        float br = sr[k1], bi = si[k1];
        sr[k0] = u00r*ar - u00i*ai + u01r*br - u01i*bi;
        si[k0] = u00r*ai + u00i*ar + u01r*bi + u01i*br;
        sr[k1] = u10r*ar - u10i*ai + u11r*br - u11i*bi;
        si[k1] = u10r*ai + u10i*ar + u11r*bi + u11i*br;
      }
    }
  }
}

template<int C, int T>
DEVFN void cnot_gate(int lane, float (&sr)[4], float (&si)[4]) {
  constexpr int PC = 7 - C, PT = 7 - T;
  if constexpr (PT >= 2) {
    constexpr int M = 1 << (PT - 2);
    #pragma unroll
    for (int k = 0; k < 4; ++k) {
      float orr = shxor(sr[k], M);
      float oii = shxor(si[k], M);
      bool ctrl;
      if constexpr (PC >= 2) ctrl = ((lane >> (PC - 2)) & 1) != 0;
      else                   ctrl = ((k >> PC) & 1) != 0;
      if (ctrl) { sr[k] = orr; si[k] = oii; }
    }
  } else {
    float tr[4], ti[4];
    #pragma unroll
    for (int k = 0; k < 4; ++k) { tr[k] = sr[k]; ti[k] = si[k]; }
    #pragma unroll
    for (int k = 0; k < 4; ++k) {
      bool ctrl;
      if constexpr (PC >= 2) ctrl = ((lane >> (PC - 2)) & 1) != 0;
      else                   ctrl = ((k >> PC) & 1) != 0;
      if (ctrl) { sr[k] = tr[k ^ (1 << PT)]; si[k] = ti[k ^ (1 << PT)]; }
    }
  }
}

// ---------------------------------------------------------------------------
// Prep (identical to validated R5/R7): blocks 0..255 simulate basis state
// e_col and scatter into per-wave MFMA fragment layout:
//   Bfrag[((ch*4 + q)*8 + ks)*512 + (kg*16 + cf)*8 + e]
// Block 256: folded LayerNorm/FC stats.
// ---------------------------------------------------------------------------
__global__ __launch_bounds__(64) void qsb_prep(
    const float* __restrict__ qw, const float* __restrict__ Wm,
    const float* __restrict__ bias,
    _Float16* __restrict__ Bfrag, float* __restrict__ stats) {
  __shared__ float uL[16 * 8];
  int bid = blockIdx.x;
  int lane = threadIdx.x;
  if (bid < 256) {
    if (lane < 16) {
      int l = lane >> 3, i = lane & 7;
      float phi = qw[l*24 + i*3 + 0];
      float th  = qw[l*24 + i*3 + 1];
      float om  = qw[l*24 + i*3 + 2];
      float cth = cosf(0.5f*th), sth = sinf(0.5f*th);
      float ap = 0.5f*(phi+om), am = 0.5f*(phi-om);
      float cap = cosf(ap), sap = sinf(ap);
      float cam = cosf(am), sam = sinf(am);
      float* u = &uL[lane*8];
      u[0] =  cap*cth; u[1] = -sap*cth;
      u[2] = -cam*sth; u[3] = -sam*sth;
      u[4] =  cam*sth; u[5] = -sam*sth;
      u[6] =  cap*cth; u[7] =  sap*cth;
    }
    __syncthreads();
    int col = bid;
    float sr[4], si[4];
    #pragma unroll
    for (int k = 0; k < 4; ++k) { sr[k] = (lane*4 + k == col) ? 1.f : 0.f; si[k] = 0.f; }
    rot_gate<0>(lane, sr, si, &uL[0*8]);
    rot_gate<1>(lane, sr, si, &uL[1*8]);
    rot_gate<2>(lane, sr, si, &uL[2*8]);
    rot_gate<3>(lane, sr, si, &uL[3*8]);
    rot_gate<4>(lane, sr, si, &uL[4*8]);
    rot_gate<5>(lane, sr, si, &uL[5*8]);
    rot_gate<6>(lane, sr, si, &uL[6*8]);
    rot_gate<7>(lane, sr, si, &uL[7*8]);
    cnot_gate<0,1>(lane, sr, si);
    cnot_gate<1,2>(lane, sr, si);
    cnot_gate<2,3>(lane, sr, si);
    cnot_gate<3,4>(lane, sr, si);
    cnot_gate<4,5>(lane, sr, si);
    cnot_gate<5,6>(lane, sr, si);
    cnot_gate<6,7>(lane, sr, si);
    cnot_gate<7,0>(lane, sr, si);
    rot_gate<0>(lane, sr, si, &uL[(8+0)*8]);
    rot_gate<1>(lane, sr, si, &uL[(8+1)*8]);
    rot_gate<2>(lane, sr, si, &uL[(8+2)*8]);
    rot_gate<3>(lane, sr, si, &uL[(8+3)*8]);
    rot_gate<4>(lane, sr, si, &uL[(8+4)*8]);
    rot_gate<5>(lane, sr, si, &uL[(8+5)*8]);
    rot_gate<6>(lane, sr, si, &uL[(8+6)*8]);
    rot_gate<7>(lane, sr, si, &uL[(8+7)*8]);
    cnot_gate<0,2>(lane, sr, si);
    cnot_gate<1,3>(lane, sr, si);
    cnot_gate<2,4>(lane, sr, si);
    cnot_gate<3,5>(lane, sr, si);
    cnot_gate<4,6>(lane, sr, si);
    cnot_gate<5,7>(lane, sr, si);
    cnot_gate<6,0>(lane, sr, si);
    cnot_gate<7,1>(lane, sr, si);
    const int ks = col >> 5, kg = (col >> 3) & 3, e = col & 7;
    #pragma unroll
    for (int k = 0; k < 4; ++k) {
      int a = lane*4 + k;
      int ch = a >> 5, nf = (a >> 4) & 1, cf = a & 15;
      int pos = (kg*16 + cf)*8 + e;
      Bfrag[((ch*4 + nf    )*8 + ks)*512 + pos] = (_Float16)sr[k];
      Bfrag[((ch*4 + 2 + nf)*8 + ks)*512 + pos] = (_Float16)si[k];
    }
  } else {
    int t = lane;
    {
      int i = t >> 3, j = t & 7;
      float s = 0.f;
      for (int c = 0; c < 64; ++c) s += Wm[i*64 + c] * Wm[j*64 + c];
      stats[16 + t] = s * 0.015625f;
    }
    if (t < 8) {
      float s = 0.f, sb = 0.f;
      for (int c = 0; c < 64; ++c) { float w = Wm[t*64 + c]; s += w; sb += w * bias[c]; }
      stats[t]     = s * 0.015625f;
      stats[8 + t] = 2.f * sb * 0.015625f;
    }
    if (t == 0) {
      float s = 0.f, s2 = 0.f;
      for (int c = 0; c < 64; ++c) { s += bias[c]; s2 += bias[c]*bias[c]; }
      stats[80] = s * 0.015625f;
      stats[81] = s2 * 0.015625f;
    }
  }
}

// ---------------------------------------------------------------------------
// Main (R14): WAVE-INDEPENDENT, zero barriers after preload.
// Each wave owns 16 batch rows end-to-end:
//   - A-fragments built in registers (lane = row cfrag, k-slice kgrp):
//     af[ks][e] = psi[row][ks*32 + kgrp*8 + e] via prefix(ks) x tail(e).
//   - For each chunk ch (8): M=16 GEMM (8 ks x 4 q MFMAs, JIT B loads),
//     probs -> wave-private Y -> S-MFMA with chunk-signed 8-col sign matrix,
//     accumulated across chunks in zacc (C operand).
//   - z -> wave-private LDS; folded LN stats; FC + LN + GELU. All DS
//     accesses are wave-private (in-order DS pipe) -> no __syncthreads.
// Amp bits: b7b6b5 = chunk, b4b3 = kgrp, b2b1b0 = e; wire w <-> bit 7-w.
// ---------------------------------------------------------------------------
__global__ __launch_bounds__(256, 4) void qsb_main(
    const float* __restrict__ pca, const _Float16* __restrict__ Bfrag,
    const float* __restrict__ statsG,
    const float* __restrict__ Wm, const float* __restrict__ bias,
    const float* __restrict__ gamma, const float* __restrict__ beta,
    float* __restrict__ out, int B) {
  __shared__ __align__(16) _Float16 YL[4 * 640];  // per-wave Y: 16 rows x 40
  __shared__ __align__(16) float zrowL[4 * 192];  // per-wave z: 16 rows x 12
  __shared__ float musigL[4 * 32];                // per-wave: 16 rows x 2
  __shared__ float Wl[512];
  __shared__ float biasL[64], gammaL[64], betaL[64];
  __shared__ float statsL[82];

  const int tid = threadIdx.x;
  const int wid = tid >> 6, lane = tid & 63;
  const int cfrag = lane & 15, kgrp = lane >> 4;
  const int r0w = blockIdx.x * 64 + wid * 16;   // this wave's 16 rows

  // ---- phase 0: block-common preloads, then the ONLY barrier ----
  #pragma unroll
  for (int i = tid; i < 512; i += 256) Wl[i] = Wm[i];
  if (tid >= 256 - 64) {
    int t = tid - (256 - 64);
    biasL[t] = bias[t]; gammaL[t] = gamma[t]; betaL[t] = beta[t];
  }
  if (tid < 82) statsL[tid] = statsG[tid];
  __syncthreads();

  _Float16* Yw = &YL[wid * 640];
  float* zrowW = &zrowL[wid * 192];
  float* musigW = &musigL[wid * 32];

  // ---- phase 1: A-fragments in registers (row = cfrag, k-slice = kgrp) ----
  f16x8 af[8];
  {
    const int r = r0w + cfrag;
    float c[8], s[8];
    #pragma unroll
    for (int w = 0; w < 8; ++w) { c[w] = 1.f; s[w] = 0.f; }
    if (r < B) {
      #pragma unroll
      for (int w = 0; w < 8; ++w) {
        float x = pca[r*8 + w];
        float sg = __builtin_amdgcn_rcpf(1.f + __expf(-x));
        float ang = 1.5707963267948966f * sg;
        c[w] = __cosf(ang); s[w] = __sinf(ang);
      }
    }
    // tail over e bits: e bit p <-> wire 7-p
    float tail[8];
    tail[0] = 1.f;
    #pragma unroll
    for (int p = 0; p < 3; ++p) {
      const int w = 7 - p;
      const int sz = 1 << p;
      #pragma unroll
      for (int i = 0; i < (1 << p); ++i) {
        tail[i + sz] = tail[i] * s[w];
        tail[i]      = tail[i] * c[w];
      }
    }
    // prefix over ks bits: ks bit p <-> wire 2-p; seeded with kgrp (wires 3,4)
    float pre[8];
    pre[0] = ((kgrp & 2) ? s[3] : c[3]) * ((kgrp & 1) ? s[4] : c[4]);
    #pragma unroll
    for (int p = 0; p < 3; ++p) {
      const int w = 2 - p;
      const int sz = 1 << p;
      #pragma unroll
      for (int i = 0; i < (1 << p); ++i) {
        pre[i + sz] = pre[i] * s[w];
        pre[i]      = pre[i] * c[w];
      }
    }
    #pragma unroll
    for (int ks = 0; ks < 8; ++ks) {
      #pragma unroll
      for (int e = 0; e < 8; ++e)
        af[ks][e] = (_Float16)(pre[ks] * tail[e]);
    }
  }

  // ---- phases 2+3: 8 chunks, zacc accumulates z via S-MFMA C operand ----
  f32x4 zacc = (f32x4){0.f, 0.f, 0.f, 0.f};
  #pragma unroll
  for (int ch = 0; ch < 8; ++ch) {
    const _Float16* Bw = Bfrag + (size_t)ch * 16384 + lane*8;

    f32x4 acc[4];
    #pragma unroll
    for (int q = 0; q < 4; ++q) acc[q] = (f32x4){0.f, 0.f, 0.f, 0.f};

    #pragma unroll
    for (int ks = 0; ks < 8; ++ks) {
      f16x8 bq0 = *(const f16x8*)(Bw + (0*8 + ks)*512);
      f16x8 bq1 = *(const f16x8*)(Bw + (1*8 + ks)*512);
      f16x8 bq2 = *(const f16x8*)(Bw + (2*8 + ks)*512);
      f16x8 bq3 = *(const f16x8*)(Bw + (3*8 + ks)*512);
      acc[0] = __builtin_amdgcn_mfma_f32_16x16x32_f16(af[ks], bq0, acc[0], 0, 0, 0);
      acc[1] = __builtin_amdgcn_mfma_f32_16x16x32_f16(af[ks], bq1, acc[1], 0, 0, 0);
      acc[2] = __builtin_amdgcn_mfma_f32_16x16x32_f16(af[ks], bq2, acc[2], 0, 0, 0);
      acc[3] = __builtin_amdgcn_mfma_f32_16x16x32_f16(af[ks], bq3, acc[3], 0, 0, 0);
    }

    // probs -> wave-private Y (row = kgrp*4+j, col = nf*16 + cfrag)
    #pragma unroll
    for (int nf = 0; nf < 2; ++nf) {
      #pragma unroll
      for (int j = 0; j < 4; ++j) {
        float re = acc[nf][j], im = acc[2 + nf][j];
        float p = re*re + im*im;
        Yw[(kgrp*4 + j)*40 + nf*16 + cfrag] = (_Float16)p;
      }
    }

    // chunk-signed 8-col sign matrix:
    //   col 0,1,2 = wires 0,1,2: +-1 by chunk bits 2,1,0
    //   col 3..7  = wires 3..7 : sign by amp bits 4..0 (kgrp/e)
    f16x8 sfc;
    #pragma unroll
    for (int e = 0; e < 8; ++e) {
      float v;
      if      (cfrag == 0) v = (ch & 4) ? -1.f : 1.f;   // wire 0 (amp b7)
      else if (cfrag == 1) v = (ch & 2) ? -1.f : 1.f;   // wire 1 (amp b6)
      else if (cfrag == 2) v = (ch & 1) ? -1.f : 1.f;   // wire 2 (amp b5)
      else if (cfrag == 3) v = (kgrp & 2) ? -1.f : 1.f; // wire 3 (amp b4)
      else if (cfrag == 4) v = (kgrp & 1) ? -1.f : 1.f; // wire 4 (amp b3)
      else if (cfrag == 5) v = (e & 4) ? -1.f : 1.f;    // wire 5 (amp b2)
      else if (cfrag == 6) v = (e & 2) ? -1.f : 1.f;    // wire 6 (amp b1)
      else if (cfrag == 7) v = (e & 1) ? -1.f : 1.f;    // wire 7 (amp b0)
      else v = 0.f;
      sfc[e] = (_Float16)v;
    }

    // wave-private read-back (in-order DS) + accumulating S-MFMA
    f16x8 yfrag = *(const f16x8*)&Yw[(lane & 15)*40 + kgrp*8];
    zacc = __builtin_amdgcn_mfma_f32_16x16x32_f16(yfrag, sfc, zacc, 0, 0, 0);
  }

  // ---- z -> wave-private LDS (stride 12 floats, 16B-aligned rows) ----
  if (cfrag < 8) {
    #pragma unroll
    for (int j = 0; j < 4; ++j)
      zrowW[(kgrp*4 + j)*12 + cfrag] = zacc[j];
  }

  // ---- phase 5: folded LN stats (2 passes x 8 rows x 8 wires) ----
  #pragma unroll
  for (int pass = 0; pass < 2; ++pass) {
    const int row = pass*8 + (lane >> 3), w = lane & 7;
    f32x4 zlo = *(const f32x4*)&zrowW[row*12];
    f32x4 zhi = *(const f32x4*)&zrowW[row*12 + 4];
    float zj[8] = {zlo[0], zlo[1], zlo[2], zlo[3], zhi[0], zhi[1], zhi[2], zhi[3]};
    float qi = statsL[8 + w];
    #pragma unroll
    for (int j = 0; j < 8; ++j) qi += statsL[16 + w*8 + j] * zj[j];
    float e2p = zj[w] * qi;
    float mup = statsL[w] * zj[w];
    e2p += shxor(e2p, 1); e2p += shxor(e2p, 2); e2p += shxor(e2p, 4);
    mup += shxor(mup, 1); mup += shxor(mup, 2); mup += shxor(mup, 4);
    if (w == 0) {
      float mu = mup + statsL[80];
      float e2 = e2p + statsL[81];
      float var = e2 - mu*mu;
      musigW[row*2]     = mu;
      musigW[row*2 + 1] = rsqrtf(fmaxf(var, 0.f) + 1e-5f);
    }
  }

  // ---- phase 6: FC + LN + exact GELU (16 rows, lane = out col) ----
  {
    float wcol[8];
    #pragma unroll
    for (int i = 0; i < 8; ++i) wcol[i] = Wl[i*64 + lane];
    const float bl = biasL[lane], gl = gammaL[lane], btl = betaL[lane];
    #pragma unroll
    for (int row = 0; row < 16; ++row) {
      f32x4 zlo = *(const f32x4*)&zrowW[row*12];
      f32x4 zhi = *(const f32x4*)&zrowW[row*12 + 4];
      float h = bl;
      h = fmaf(zlo[0], wcol[0], h); h = fmaf(zlo[1], wcol[1], h);
      h = fmaf(zlo[2], wcol[2], h); h = fmaf(zlo[3], wcol[3], h);
      h = fmaf(zhi[0], wcol[4], h); h = fmaf(zhi[1], wcol[5], h);
      h = fmaf(zhi[2], wcol[6], h); h = fmaf(zhi[3], wcol[7], h);
      float hn = (h - musigW[row*2]) * musigW[row*2 + 1] * gl + btl;
      float ge = 0.5f * hn * (1.f + erff(hn * 0.70710678118654752f));
      const int gr = r0w + row;
      if (gr < B) out[gr*64 + lane] = ge;
    }
  }
}

extern "C" void kernel_launch(void* const* d_in, const int* in_sizes, int n_in,
                              void* d_out, int out_size, void* d_ws, size_t ws_size,
                              hipStream_t stream) {
  const float* pca   = (const float*)d_in[0];
  const float* qw    = (const float*)d_in[1];
  const float* Wm    = (const float*)d_in[2];
  const float* bias  = (const float*)d_in[3];
  const float* gamma = (const float*)d_in[4];
  const float* beta  = (const float*)d_in[5];
  float* out = (float*)d_out;

  _Float16* Bfrag = (_Float16*)d_ws;                   // 512*256*2 = 256 KiB
  float* stats = (float*)((char*)d_ws + 512*256*2);    // 82 floats

  int B = in_sizes[0] / 8;

  hipLaunchKernelGGL(qsb_prep, dim3(257), dim3(64), 0, stream, qw, Wm, bias, Bfrag, stats);
  int blocks = (B + 63) / 64;   // 64 rows/block (4 independent waves x 16)
  hipLaunchKernelGGL(qsb_main, dim3(blocks), dim3(256), 0, stream,
                     pca, Bfrag, stats, Wm, bias, gamma, beta, out, B);
}

// Round 15
// 30.455 us; speedup vs baseline: 2.8310x; 1.6613x over previous
//
#include <hip/hip_runtime.h>
#include <math.h>

#define DEVFN __device__ __forceinline__

typedef __attribute__((ext_vector_type(8))) _Float16 f16x8;
typedef __attribute__((ext_vector_type(4))) float f32x4;

DEVFN float shxor(float v, int m) { return __shfl_xor(v, m, 64); }

// ---------------------------------------------------------------------------
// Gate machinery (verified R1/R3/R4/R5).
// State layout: amplitude index a (8 bits) = lane*4 + k; wire w <-> bit 7-w.
// ---------------------------------------------------------------------------
template<int W>
DEVFN void rot_gate(int lane, float (&sr)[4], float (&si)[4], const float* u) {
  const float u00r=u[0], u00i=u[1], u01r=u[2], u01i=u[3];
  const float u10r=u[4], u10i=u[5], u11r=u[6], u11i=u[7];
  if constexpr (W <= 5) {
    constexpr int M = 1 << (5 - W);
    const bool hi = (lane & M) != 0;
    const float cmr = hi ? u11r : u00r, cmi = hi ? u11i : u00i;
    const float cor = hi ? u10r : u01r, coi = hi ? u10i : u01i;
    #pragma unroll
    for (int k = 0; k < 4; ++k) {
      float orr = shxor(sr[k], M);
      float oii = shxor(si[k], M);
      float nr = cmr*sr[k] - cmi*si[k] + cor*orr - coi*oii;
      float ni = cmr*si[k] + cmi*sr[k] + cor*oii + coi*orr;
      sr[k] = nr; si[k] = ni;
    }
  } else {
    constexpr int KB = (W == 6) ? 2 : 1;
    #pragma unroll
    for (int k0 = 0; k0 < 4; ++k0) {
      if ((k0 & KB) == 0) {
        const int k1 = k0 | KB;
        float ar = sr[k0], ai = si[k0];
        float br = sr[k1], bi = si[k1];
        sr[k0] = u00r*ar - u00i*ai + u01r*br - u01i*bi;
        si[k0] = u00r*ai + u00i*ar + u01r*bi + u01i*br;
        sr[k1] = u10r*ar - u10i*ai + u11r*br - u11i*bi;
        si[k1] = u10r*ai + u10i*ar + u11r*bi + u11i*br;
      }
    }
  }
}

template<int C, int T>
DEVFN void cnot_gate(int lane, float (&sr)[4], float (&si)[4]) {
  constexpr int PC = 7 - C, PT = 7 - T;
  if constexpr (PT >= 2) {
    constexpr int M = 1 << (PT - 2);
    #pragma unroll
    for (int k = 0; k < 4; ++k) {
      float orr = shxor(sr[k], M);
      float oii = shxor(si[k], M);
      bool ctrl;
      if constexpr (PC >= 2) ctrl = ((lane >> (PC - 2)) & 1) != 0;
      else                   ctrl = ((k >> PC) & 1) != 0;
      if (ctrl) { sr[k] = orr; si[k] = oii; }
    }
  } else {
    float tr[4], ti[4];
    #pragma unroll
    for (int k = 0; k < 4; ++k) { tr[k] = sr[k]; ti[k] = si[k]; }
    #pragma unroll
    for (int k = 0; k < 4; ++k) {
      bool ctrl;
      if constexpr (PC >= 2) ctrl = ((lane >> (PC - 2)) & 1) != 0;
      else                   ctrl = ((k >> PC) & 1) != 0;
      if (ctrl) { sr[k] = tr[k ^ (1 << PT)]; si[k] = ti[k ^ (1 << PT)]; }
    }
  }
}

// ---------------------------------------------------------------------------
// Prep (identical to validated R5/R7): blocks 0..255 simulate basis state
// e_col and scatter into per-wave MFMA fragment layout:
//   Bfrag[((ch*4 + q)*8 + ks)*512 + (kg*16 + cf)*8 + e]
// Block 256: folded LayerNorm/FC stats.
// ---------------------------------------------------------------------------
__global__ __launch_bounds__(64) void qsb_prep(
    const float* __restrict__ qw, const float* __restrict__ Wm,
    const float* __restrict__ bias,
    _Float16* __restrict__ Bfrag, float* __restrict__ stats) {
  __shared__ float uL[16 * 8];
  int bid = blockIdx.x;
  int lane = threadIdx.x;
  if (bid < 256) {
    if (lane < 16) {
      int l = lane >> 3, i = lane & 7;
      float phi = qw[l*24 + i*3 + 0];
      float th  = qw[l*24 + i*3 + 1];
      float om  = qw[l*24 + i*3 + 2];
      float cth = cosf(0.5f*th), sth = sinf(0.5f*th);
      float ap = 0.5f*(phi+om), am = 0.5f*(phi-om);
      float cap = cosf(ap), sap = sinf(ap);
      float cam = cosf(am), sam = sinf(am);
      float* u = &uL[lane*8];
      u[0] =  cap*cth; u[1] = -sap*cth;
      u[2] = -cam*sth; u[3] = -sam*sth;
      u[4] =  cam*sth; u[5] = -sam*sth;
      u[6] =  cap*cth; u[7] =  sap*cth;
    }
    __syncthreads();
    int col = bid;
    float sr[4], si[4];
    #pragma unroll
    for (int k = 0; k < 4; ++k) { sr[k] = (lane*4 + k == col) ? 1.f : 0.f; si[k] = 0.f; }
    rot_gate<0>(lane, sr, si, &uL[0*8]);
    rot_gate<1>(lane, sr, si, &uL[1*8]);
    rot_gate<2>(lane, sr, si, &uL[2*8]);
    rot_gate<3>(lane, sr, si, &uL[3*8]);
    rot_gate<4>(lane, sr, si, &uL[4*8]);
    rot_gate<5>(lane, sr, si, &uL[5*8]);
    rot_gate<6>(lane, sr, si, &uL[6*8]);
    rot_gate<7>(lane, sr, si, &uL[7*8]);
    cnot_gate<0,1>(lane, sr, si);
    cnot_gate<1,2>(lane, sr, si);
    cnot_gate<2,3>(lane, sr, si);
    cnot_gate<3,4>(lane, sr, si);
    cnot_gate<4,5>(lane, sr, si);
    cnot_gate<5,6>(lane, sr, si);
    cnot_gate<6,7>(lane, sr, si);
    cnot_gate<7,0>(lane, sr, si);
    rot_gate<0>(lane, sr, si, &uL[(8+0)*8]);
    rot_gate<1>(lane, sr, si, &uL[(8+1)*8]);
    rot_gate<2>(lane, sr, si, &uL[(8+2)*8]);
    rot_gate<3>(lane, sr, si, &uL[(8+3)*8]);
    rot_gate<4>(lane, sr, si, &uL[(8+4)*8]);
    rot_gate<5>(lane, sr, si, &uL[(8+5)*8]);
    rot_gate<6>(lane, sr, si, &uL[(8+6)*8]);
    rot_gate<7>(lane, sr, si, &uL[(8+7)*8]);
    cnot_gate<0,2>(lane, sr, si);
    cnot_gate<1,3>(lane, sr, si);
    cnot_gate<2,4>(lane, sr, si);
    cnot_gate<3,5>(lane, sr, si);
    cnot_gate<4,6>(lane, sr, si);
    cnot_gate<5,7>(lane, sr, si);
    cnot_gate<6,0>(lane, sr, si);
    cnot_gate<7,1>(lane, sr, si);
    const int ks = col >> 5, kg = (col >> 3) & 3, e = col & 7;
    #pragma unroll
    for (int k = 0; k < 4; ++k) {
      int a = lane*4 + k;
      int ch = a >> 5, nf = (a >> 4) & 1, cf = a & 15;
      int pos = (kg*16 + cf)*8 + e;
      Bfrag[((ch*4 + nf    )*8 + ks)*512 + pos] = (_Float16)sr[k];
      Bfrag[((ch*4 + 2 + nf)*8 + ks)*512 + pos] = (_Float16)si[k];
    }
  } else {
    int t = lane;
    {
      int i = t >> 3, j = t & 7;
      float s = 0.f;
      for (int c = 0; c < 64; ++c) s += Wm[i*64 + c] * Wm[j*64 + c];
      stats[16 + t] = s * 0.015625f;
    }
    if (t < 8) {
      float s = 0.f, sb = 0.f;
      for (int c = 0; c < 64; ++c) { float w = Wm[t*64 + c]; s += w; sb += w * bias[c]; }
      stats[t]     = s * 0.015625f;
      stats[8 + t] = 2.f * sb * 0.015625f;
    }
    if (t == 0) {
      float s = 0.f, s2 = 0.f;
      for (int c = 0; c < 64; ++c) { s += bias[c]; s2 += bias[c]*bias[c]; }
      stats[80] = s * 0.015625f;
      stats[81] = s2 * 0.015625f;
    }
  }
}

// load one ks-step's 4 q-fragments into a statically-named bank
#define LOADQ(bank, ksv) \
  bank##0 = *(const f16x8*)(Bw + (0*8 + (ksv))*512); \
  bank##1 = *(const f16x8*)(Bw + (1*8 + (ksv))*512); \
  bank##2 = *(const f16x8*)(Bw + (2*8 + (ksv))*512); \
  bank##3 = *(const f16x8*)(Bw + (3*8 + (ksv))*512);

// consume one bank: 2 m-tiles x 4 q MFMAs against A3 slice ksv
#define STEPK(bank, ksv) { \
  f16x8 af0 = *(const f16x8*)&A3[(((ksv)*2 + 0)*16 + cfrag)*32 + (kgrp ^ ((ksv) & 3))*8]; \
  f16x8 af1 = *(const f16x8*)&A3[(((ksv)*2 + 1)*16 + cfrag)*32 + (kgrp ^ ((ksv) & 3))*8]; \
  acc[0][0] = __builtin_amdgcn_mfma_f32_16x16x32_f16(af0, bank##0, acc[0][0], 0, 0, 0); \
  acc[1][0] = __builtin_amdgcn_mfma_f32_16x16x32_f16(af1, bank##0, acc[1][0], 0, 0, 0); \
  acc[0][1] = __builtin_amdgcn_mfma_f32_16x16x32_f16(af0, bank##1, acc[0][1], 0, 0, 0); \
  acc[1][1] = __builtin_amdgcn_mfma_f32_16x16x32_f16(af1, bank##1, acc[1][1], 0, 0, 0); \
  acc[0][2] = __builtin_amdgcn_mfma_f32_16x16x32_f16(af0, bank##2, acc[0][2], 0, 0, 0); \
  acc[1][2] = __builtin_amdgcn_mfma_f32_16x16x32_f16(af1, bank##2, acc[1][2], 0, 0, 0); \
  acc[0][3] = __builtin_amdgcn_mfma_f32_16x16x32_f16(af0, bank##3, acc[0][3], 0, 0, 0); \
  acc[1][3] = __builtin_amdgcn_mfma_f32_16x16x32_f16(af1, bank##3, acc[1][3], 0, 0, 0); \
}

#define SBAR __builtin_amdgcn_sched_barrier(0)

// ---------------------------------------------------------------------------
// Main (R15 = R7 + sched_barrier-forced B pipeline): 32 rows/block,
// 256 threads (4 waves), grid = B/32 = 1024 blocks. Wave wid owns chunks
// {2*wid, 2*wid+1}. Per chunk the 8 ks-steps run a 4-bank lookahead-3
// register pipeline: each step issues the ks+3 bank's 4 x 1KB loads, then
// sched_barrier(0) (compiler cannot sink loads / hoist MFMAs across), then
// the 8 MFMAs of the current bank -> 12-16 loads always in flight.
// Epilogue/phases 4-6 identical to verified R7.
// Amp bits: b7b6b5 = chunk, b4 = nf, b3..b0 = cf; wire w <-> bit 7-w.
// ---------------------------------------------------------------------------
__global__ __launch_bounds__(256, 3) void qsb_main(
    const float* __restrict__ pca, const _Float16* __restrict__ Bfrag,
    const float* __restrict__ statsG,
    const float* __restrict__ Wm, const float* __restrict__ bias,
    const float* __restrict__ gamma, const float* __restrict__ beta,
    float* __restrict__ out, int B) {
  // A3: element (row,k): ((ks*2 + m)*16 + cf)*32 + (kg^(ks&3))*8 + e  (16 KB)
  __shared__ __align__(16) _Float16 A3[8192];
  __shared__ __align__(16) _Float16 YL[4 * 1280];  // per-wave Y, stride 40 (10 KB)
  __shared__ float zpart[2304];   // [ch=8][row=32][9], slots 0..5 used (9 KB)
  __shared__ float zrow[256];     // [row=32][8]
  __shared__ float musig[64];     // [row=32][2]
  __shared__ float Wl[512];
  __shared__ float biasL[64], gammaL[64], betaL[64];
  __shared__ float statsL[82];

  const int tid = threadIdx.x;
  const int wid = tid >> 6, lane = tid & 63;
  const int cfrag = lane & 15, kgrp = lane >> 4;
  const int r0 = blockIdx.x * 32;

  // ---- phase 0: preloads ----
  #pragma unroll
  for (int i = tid; i < 512; i += 256) Wl[i] = Wm[i];
  if (tid >= 256 - 64) {
    int t = tid - (256 - 64);
    biasL[t] = bias[t]; gammaL[t] = gamma[t]; betaL[t] = beta[t];
  }
  if (tid < 82) statsL[tid] = statsG[tid];

  // ---- sign fragment for the S-MFMA (B-frag: col=cfrag, k=kgrp*8+e) ----
  f16x8 sfrag;
  #pragma unroll
  for (int e = 0; e < 8; ++e) {
    float v;
    if      (cfrag == 0) v = 1.f;                        // T (chunk total)
    else if (cfrag == 1) v = (kgrp & 2) ? -1.f : 1.f;    // wire 3 (a bit4)
    else if (cfrag == 2) v = (kgrp & 1) ? -1.f : 1.f;    // wire 4 (a bit3)
    else if (cfrag == 3) v = (e & 4)    ? -1.f : 1.f;    // wire 5 (a bit2)
    else if (cfrag == 4) v = (e & 2)    ? -1.f : 1.f;    // wire 6 (a bit1)
    else if (cfrag == 5) v = (e & 1)    ? -1.f : 1.f;    // wire 7 (a bit0)
    else v = 0.f;
    sfrag[e] = (_Float16)v;
  }

  // ---- phase 1: A build (8 threads/row, 32 k each), fast trig ----
  {
    const int rl = tid >> 3, tq = tid & 7;
    const int r = r0 + rl;
    float cv[8], sv[8];
    #pragma unroll
    for (int w = 0; w < 8; ++w) { cv[w] = 1.f; sv[w] = 0.f; }
    if (r < B) {
      #pragma unroll
      for (int w = 0; w < 8; ++w) {
        float x = pca[r*8 + w];
        float sg = __builtin_amdgcn_rcpf(1.f + __expf(-x));
        float ang = 1.5707963267948966f * sg;
        cv[w] = __cosf(ang); sv[w] = __sinf(ang);
      }
    }
    float base = ((tq & 4) ? sv[0] : cv[0]) * ((tq & 2) ? sv[1] : cv[1])
               * ((tq & 1) ? sv[2] : cv[2]);
    float arr[32];
    arr[0] = base;
    #pragma unroll
    for (int p = 0; p < 5; ++p) {
      const int w = 7 - p;
      const int sz = 1 << p;
      #pragma unroll
      for (int i = 0; i < (1 << p); ++i) {
        arr[i + sz] = arr[i] * sv[w];
        arr[i]      = arr[i] * cv[w];
      }
    }
    _Float16* dstBase = &A3[((tq*2 + (rl >> 4))*16 + (rl & 15))*32];
    #pragma unroll
    for (int ib = 0; ib < 4; ++ib) {
      f16x8 v;
      #pragma unroll
      for (int j = 0; j < 8; ++j) v[j] = (_Float16)arr[ib*8 + j];
      *(f16x8*)(dstBase + (ib ^ (tq & 3))*8) = v;
    }
  }
  __syncthreads();   // barrier 1: A3 ready

  // ---- phases 2+3, per chunk: forced 4-bank lookahead-3 pipeline ----
  _Float16* Yw = &YL[wid * 1280];
  #pragma unroll
  for (int c = 0; c < 2; ++c) {
    const int ch = wid*2 + c;
    const _Float16* Bw = Bfrag + (size_t)(ch*4)*8*512 + lane*8;

    f32x4 acc[2][4];
    #pragma unroll
    for (int m = 0; m < 2; ++m)
      #pragma unroll
      for (int q = 0; q < 4; ++q) acc[m][q] = (f32x4){0.f, 0.f, 0.f, 0.f};

    f16x8 bA0, bA1, bA2, bA3, bB0, bB1, bB2, bB3;
    f16x8 bC0, bC1, bC2, bC3, bD0, bD1, bD2, bD3;

    LOADQ(bA, 0) LOADQ(bB, 1) LOADQ(bC, 2)
    SBAR;
    LOADQ(bD, 3) SBAR; STEPK(bA, 0)
    LOADQ(bA, 4) SBAR; STEPK(bB, 1)
    LOADQ(bB, 5) SBAR; STEPK(bC, 2)
    LOADQ(bC, 6) SBAR; STEPK(bD, 3)
    LOADQ(bD, 7) SBAR; STEPK(bA, 4)
    STEPK(bB, 5)
    STEPK(bC, 6)
    STEPK(bD, 7)

    // probs -> wave-private Y (f16, A-frag-transposed via LDS, stride 40)
    #pragma unroll
    for (int m = 0; m < 2; ++m) {
      #pragma unroll
      for (int nf = 0; nf < 2; ++nf) {
        #pragma unroll
        for (int j = 0; j < 4; ++j) {
          float re = acc[m][nf][j], im = acc[m][2 + nf][j];
          float p = re*re + im*im;
          Yw[m*640 + (kgrp*4 + j)*40 + nf*16 + cfrag] = (_Float16)p;
        }
      }
    }
    // wave-private read-back (in-order DS pipe; no barrier needed)
    #pragma unroll
    for (int m = 0; m < 2; ++m) {
      f16x8 yfrag = *(const f16x8*)&Yw[m*640 + (lane & 15)*40 + kgrp*8];
      f32x4 d = __builtin_amdgcn_mfma_f32_16x16x32_f16(yfrag, sfrag, (f32x4){0.f,0.f,0.f,0.f}, 0, 0, 0);
      if (cfrag < 6) {
        #pragma unroll
        for (int j = 0; j < 4; ++j)
          zpart[(ch*32 + m*16 + kgrp*4 + j)*9 + cfrag] = d[j];
      }
    }
  }
  __syncthreads();   // barrier 2: zpart ready

  // ---- phase 4+5: combine chunks + LN stats (thread=(row,wire)) ----
  {
    const int row = tid >> 3, w = tid & 7;
    const int slot = (w < 3) ? 0 : (w - 2);
    const int sm = (w == 0) ? 4 : (w == 1) ? 2 : (w == 2) ? 1 : 0;
    float z = 0.f;
    #pragma unroll
    for (int ch = 0; ch < 8; ++ch) {
      float v = zpart[(ch*32 + row)*9 + slot];
      z += (ch & sm) ? -v : v;
    }
    zrow[row*8 + w] = z;
    // same wave wrote all 8 slots of this row -> in-order DS, read back
    f32x4 zlo = *(const f32x4*)&zrow[row*8];
    f32x4 zhi = *(const f32x4*)&zrow[row*8 + 4];
    float zj[8] = {zlo[0], zlo[1], zlo[2], zlo[3], zhi[0], zhi[1], zhi[2], zhi[3]};
    float qi = statsL[8 + w];
    #pragma unroll
    for (int j = 0; j < 8; ++j) qi += statsL[16 + w*8 + j] * zj[j];
    float e2p = zj[w] * qi;
    float mup = statsL[w] * zj[w];
    e2p += shxor(e2p, 1); e2p += shxor(e2p, 2); e2p += shxor(e2p, 4);
    mup += shxor(mup, 1); mup += shxor(mup, 2); mup += shxor(mup, 4);
    if (w == 0) {
      float mu = mup + statsL[80];
      float e2 = e2p + statsL[81];
      float var = e2 - mu*mu;
      musig[row*2]     = mu;
      musig[row*2 + 1] = rsqrtf(fmaxf(var, 0.f) + 1e-5f);
    }
  }
  // no barrier: phase 6 reads only this wave's zrow/musig rows

  // ---- phase 6: FC + LN + exact GELU (8 rows per wave) ----
  #pragma unroll
  for (int rr = 0; rr < 8; ++rr) {
    const int row = wid*8 + rr;
    const int gr = r0 + row;
    float h = biasL[lane];
    #pragma unroll
    for (int i = 0; i < 8; ++i) h = fmaf(zrow[row*8 + i], Wl[i*64 + lane], h);
    float hn = (h - musig[row*2]) * musig[row*2 + 1] * gammaL[lane] + betaL[lane];
    float ge = 0.5f * hn * (1.f + erff(hn * 0.70710678118654752f));
    if (gr < B) out[gr*64 + lane] = ge;
  }
}

extern "C" void kernel_launch(void* const* d_in, const int* in_sizes, int n_in,
                              void* d_out, int out_size, void* d_ws, size_t ws_size,
                              hipStream_t stream) {
  const float* pca   = (const float*)d_in[0];
  const float* qw    = (const float*)d_in[1];
  const float* Wm    = (const float*)d_in[2];
  const float* bias  = (const float*)d_in[3];
  const float* gamma = (const float*)d_in[4];
  const float* beta  = (const float*)d_in[5];
  float* out = (float*)d_out;

  _Float16* Bfrag = (_Float16*)d_ws;                   // 512*256*2 = 256 KiB
  float* stats = (float*)((char*)d_ws + 512*256*2);    // 82 floats

  int B = in_sizes[0] / 8;

  hipLaunchKernelGGL(qsb_prep, dim3(257), dim3(64), 0, stream, qw, Wm, bias, Bfrag, stats);
  int blocks = (B + 31) / 32;
  hipLaunchKernelGGL(qsb_main, dim3(blocks), dim3(256), 0, stream,
                     pca, Bfrag, stats, Wm, bias, gamma, beta, out, B);
}